// Round 6
// baseline (1252.379 us; speedup 1.0000x reference)
//
#include <hip/hip_runtime.h>
#include <hip/hip_bf16.h>
#include <math.h>

#define D_MODEL 1024
#define D_INNER 2048
#define NSTATE  16
#define BATCH   4
#define SEQ     4096
#define MTOT    (BATCH*SEQ)      // 16384
#define SDT     2176             // dtBC row stride: 2048 dt | 16 B | 16 C | 96 pad
#define NCATP   2304             // Wcat rows padded to multiple of 256 (9 N-tiles)
#define NCHUNK  16
#define CLEN    (SEQ/NCHUNK)     // 256
#define N1      (2*D_INNER)      // 4096

typedef __attribute__((ext_vector_type(8))) __bf16 bf16x8;
typedef __attribute__((ext_vector_type(4))) float f32x4;

__device__ __forceinline__ float b2f(unsigned short u){
  return __uint_as_float(((unsigned int)u) << 16);
}
__device__ __forceinline__ unsigned short f2b(float f){
  unsigned int u = __float_as_uint(f);
  u = (u + 0x7FFFu + ((u >> 16) & 1u)) >> 16;   // RNE
  return (unsigned short)u;
}
__device__ __forceinline__ float softplus_f(float x){
  float r = log1pf(__expf(-fabsf(x)));
  return x > 0.f ? x + r : r;
}

// async 16B global -> LDS (DMA; LDS dst = wave-uniform base + lane*16)
__device__ __forceinline__ void async16(unsigned short* lds, const unsigned short* g){
  __builtin_amdgcn_global_load_lds(
      (const __attribute__((address_space(1))) unsigned int*)g,
      (__attribute__((address_space(3))) unsigned int*)lds, 16, 0, 0);
}

// ---- f32 -> bf16 convert (4 elems/thread) ----
__global__ void cvt_f2b_kernel(const float* __restrict__ src,
                               unsigned short* __restrict__ dst){
  int i = (blockIdx.x * 256 + threadIdx.x) * 4;
  float4 v = *(const float4*)(src + i);
  *(ushort2*)(dst + i)     = (ushort2){f2b(v.x), f2b(v.y)};
  *(ushort2*)(dst + i + 2) = (ushort2){f2b(v.z), f2b(v.w)};
}

// ---- build Wcat(bf16) = [W_dt(2048); W_B(16); W_C(16); zeros(224)] : 2304x2048 ----
__global__ void concat_w_kernel(const float* __restrict__ Wdt,
                                const float* __restrict__ WB,
                                const float* __restrict__ WC,
                                unsigned short* __restrict__ Wcat){
  int idx = blockIdx.x * 256 + threadIdx.x;   // 4-elem granularity
  int row = idx >> 9;                         // 2048 cols = 512 quads/row
  int q   = idx & 511;
  float4 v;
  if      (row < 2048) v = *(const float4*)(Wdt + ((size_t)row * 2048 + q * 4));
  else if (row < 2064) v = *(const float4*)(WB  + ((size_t)(row - 2048) * 2048 + q * 4));
  else if (row < 2080) v = *(const float4*)(WC  + ((size_t)(row - 2064) * 2048 + q * 4));
  else                 v = make_float4(0.f, 0.f, 0.f, 0.f);
  unsigned short* p = Wcat + (size_t)idx * 4;
  *(ushort2*)(p)     = (ushort2){f2b(v.x), f2b(v.y)};
  *(ushort2*)(p + 2) = (ushort2){f2b(v.z), f2b(v.w)};
}

// ============================================================================
// GEMM: C[M,N] = A[M,K] @ W[N,K]^T, bf16 MFMA, fp32 acc, fused epilogues.
// 256x256 tile, 512 thr = 8 waves (2m x 4n), per-wave output 128x64
// (A-frag reused 4x, B-frag 8x -> ~0.375 b128-reads/MFMA, the m201 design
// point; the 256x128 rev's 128x32/wave was 0.625 reads/MFMA -> 18% MfmaUtil).
//
// REGISTER BUDGET (the constraint that killed r1/r2/r4): 512 thr = 2
// waves/SIMD => 256 unified regs/thread. acc = 128 AGPR => arch VGPR <= 128.
// r2 demand ~140 -> ~6 regs respilled/iter (430 MB scratch). Diet here:
//   - K, GX are TEMPLATE CONSTANTS: the 12/iter runtime h*128*K 64-bit muls
//     fold to imm offsets; bm = flat/GX becomes magic-mul.
//   - A-half-grouped quadrant order: 48 frag regs max live (a[4][2]+b[2][2]).
// Estimated arch ~80-100 <= 128 -> no spill.
//
// 8-phase schedule, counted vmcnt(4) only at P4/P8 (verified in r2):
//  P1 Q(0,0) st buf1.Bh0<-t0+1   P5 Q(0,0)buf1 st buf0.Bh0<-t0+2
//  P2 Q(0,1) st buf1.Bh1<-t0+1   P6 Q(0,1)buf1 st buf0.Bh1<-t0+2
//  P3 Q(1,0) st buf0.Ah0<-t0+2   P7 Q(1,0)buf1 st buf1.Ah0<-t0+3
//  P4 Q(1,1) st buf0.Ah1<-t0+2   P8 Q(1,1)buf1 st buf1.Ah1<-t0+3
//  vmcnt(4)@P4 retires {buf1.A(prev P7/P8), buf1.B(P1/P2)} before P5 reads;
//  vmcnt(4)@P8 retires {buf0.A(P3/P4), buf0.B(P5/P6)} before next P1 reads.
//
// LDS chunk swizzle (bank-conflict-free): 16B slot s of row r holds k-chunk
// s^(r&7); stager pre-swizzles the GLOBAL address (linear LDS dst).
//
// MODE 0: split cols -> o0=xs (n<2048), o1=z (n>=2048)   [bf16 out]
// MODE 1: n<2048 -> softplus(v + bias[n]); store stride SDT (col<2176) [bf16]
// MODE 2: v * sigmoid(bias[0]); store f32 into of (row stride D_MODEL)
// ============================================================================
template<int MODE, int K, int GX>
__global__ __launch_bounds__(512, 1) void gemm_bt(
    const unsigned short* __restrict__ A,
    const unsigned short* __restrict__ W,
    unsigned short* __restrict__ o0,
    unsigned short* __restrict__ o1,
    float* __restrict__ of,
    const float* __restrict__ bias)
{
  const int tid  = threadIdx.x;
  const int lane = tid & 63;
  const int w    = tid >> 6;            // 0..7
  const int wm   = w >> 2;              // 0..1 : 128-row half of tile
  const int wn   = w & 3;               // 0..3 : 64-col chunk of tile
  const int m16  = lane & 15, q = lane >> 4;

  // XCD-aware bijective swizzle; NWG % 8 == 0 for all launches
  constexpr int NWG = GX * (MTOT / 256);
  int flat = blockIdx.y * GX + blockIdx.x;
  flat = (flat & 7) * (NWG >> 3) + (flat >> 3);
  const int bm = flat / GX;             // const divisor -> magic mul
  const int bn = flat - bm * GX;

  __shared__ unsigned short sA[2][16384];   // 2 x (256 rows x 64 k) = 2 x 32 KB
  __shared__ unsigned short sB[2][16384];

  f32x4 acc[8][4];
  #pragma unroll
  for (int i = 0; i < 8; i++)
    #pragma unroll
    for (int j = 0; j < 4; j++) acc[i][j] = (f32x4){0.f, 0.f, 0.f, 0.f};

  // stager: thread -> (row = tid>>3 within 64-row unit, slot = tid&7);
  // fetched global k-chunk = slot ^ (row&7) (pre-swizzled source)
  const int ch = (tid & 7) ^ ((tid >> 3) & 7);
  const unsigned short* Ag = A + (size_t)(bm * 256 + (tid >> 3)) * K + ch * 8;
  const unsigned short* Wg = W + (size_t)(bn * 256 + (tid >> 3)) * K + ch * 8;

  // All (h)*128*K / 64*K products are COMPILE-TIME (K template const).
#define STAGE_A(buf, h, t) do { \
    async16(&sA[buf][(h)*8192 + w*512],        Ag + (size_t)((h)*128    )*K + (t)*64); \
    async16(&sA[buf][(h)*8192 + 4096 + w*512], Ag + (size_t)((h)*128 + 64)*K + (t)*64); \
  } while(0)
#define STAGE_B(buf, h, t) do { \
    async16(&sB[buf][(h)*8192 + w*512],        Wg + (size_t)((h)*128    )*K + (t)*64); \
    async16(&sB[buf][(h)*8192 + 4096 + w*512], Wg + (size_t)((h)*128 + 64)*K + (t)*64); \
  } while(0)

  // fragment reads: row r, k-chunk kc=(kk*4+q) lives at slot kc^(r&7); r&7==m16&7
#define LDA(dst, buf, mh) do { \
    _Pragma("unroll") for (int mt = 0; mt < 4; mt++) \
    _Pragma("unroll") for (int kk = 0; kk < 2; kk++) { \
      const int row_ = wm*128 + (mh)*64 + mt*16 + m16; \
      dst[mt][kk] = *(const bf16x8*)&sA[buf][row_*64 + (((kk*4 + q) ^ (m16 & 7)) << 3)]; \
    } } while(0)
#define LDB(dst, buf, nh) do { \
    _Pragma("unroll") for (int nt = 0; nt < 2; nt++) \
    _Pragma("unroll") for (int kk = 0; kk < 2; kk++) { \
      const int row_ = wn*64 + (nh)*32 + nt*16 + m16; \
      dst[nt][kk] = *(const bf16x8*)&sB[buf][row_*64 + (((kk*4 + q) ^ (m16 & 7)) << 3)]; \
    } } while(0)

#define MMAQ(Aa, Bb, MH, NH) do { \
    __builtin_amdgcn_s_setprio(1); \
    _Pragma("unroll") for (int kk = 0; kk < 2; kk++) \
    _Pragma("unroll") for (int mt = 0; mt < 4; mt++) \
    _Pragma("unroll") for (int nt = 0; nt < 2; nt++) \
      acc[(MH)*4 + mt][(NH)*2 + nt] = __builtin_amdgcn_mfma_f32_16x16x32_bf16( \
          Aa[mt][kk], Bb[nt][kk], acc[(MH)*4 + mt][(NH)*2 + nt], 0, 0, 0); \
    __builtin_amdgcn_s_setprio(0); \
    __builtin_amdgcn_sched_barrier(0); \
  } while(0)

#define BAR()  asm volatile("s_barrier" ::: "memory")
#define LGK0() do { asm volatile("s_waitcnt lgkmcnt(0)" ::: "memory"); \
                    __builtin_amdgcn_sched_barrier(0); } while(0)

  // ---- prologue: buf0 <- tile0 (4 half-tiles), buf1.A <- tile1 (2 half-tiles)
  STAGE_A(0, 0, 0); STAGE_A(0, 1, 0); STAGE_B(0, 0, 0); STAGE_B(0, 1, 0);
  STAGE_A(1, 0, 1); STAGE_A(1, 1, 1);
  asm volatile("s_waitcnt vmcnt(4)" ::: "memory");   // buf0 complete; buf1.A in flight
  BAR();

  auto run_iter = [&](int t0, bool last) {
    bf16x8 a[4][2], b[2][2];
    // ---- P1: Q(0,0) on buf0 ----
    LDA(a, 0, 0); LDB(b, 0, 0);
    STAGE_B(1, 0, t0 + 1);
    BAR(); LGK0();
    MMAQ(a, b, 0, 0);
    BAR();
    // ---- P2: Q(0,1) on buf0 (A-half0 held) ----
    LDB(b, 0, 1);
    STAGE_B(1, 1, t0 + 1);
    BAR(); LGK0();
    MMAQ(a, b, 0, 1);
    BAR();
    // ---- P3: Q(1,0) on buf0 (reload A-half1 into same regs) ----
    LDA(a, 0, 1); LDB(b, 0, 0);
    if (!last) STAGE_A(0, 0, t0 + 2);
    BAR(); LGK0();
    MMAQ(a, b, 1, 0);
    BAR();
    // ---- P4: Q(1,1) on buf0 ----
    LDB(b, 0, 1);
    if (!last) STAGE_A(0, 1, t0 + 2);
    BAR(); LGK0();
    MMAQ(a, b, 1, 1);
    if (last) asm volatile("s_waitcnt vmcnt(0)" ::: "memory");
    else      asm volatile("s_waitcnt vmcnt(4)" ::: "memory");
    BAR();
    // ---- P5: Q(0,0) on buf1 ----
    LDA(a, 1, 0); LDB(b, 1, 0);
    if (!last) STAGE_B(0, 0, t0 + 2);
    BAR(); LGK0();
    MMAQ(a, b, 0, 0);
    BAR();
    // ---- P6: Q(0,1) on buf1 ----
    LDB(b, 1, 1);
    if (!last) STAGE_B(0, 1, t0 + 2);
    BAR(); LGK0();
    MMAQ(a, b, 0, 1);
    BAR();
    // ---- P7: Q(1,0) on buf1 ----
    LDA(a, 1, 1); LDB(b, 1, 0);
    if (!last) STAGE_A(1, 0, t0 + 3);
    BAR(); LGK0();
    MMAQ(a, b, 1, 0);
    BAR();
    // ---- P8: Q(1,1) on buf1 ----
    LDB(b, 1, 1);
    if (!last) STAGE_A(1, 1, t0 + 3);
    BAR(); LGK0();
    MMAQ(a, b, 1, 1);
    if (!last) asm volatile("s_waitcnt vmcnt(4)" ::: "memory");
    BAR();
  };

  constexpr int NIT = K >> 7;          // K / 128 (two 64-K tiles per iter)
  #pragma unroll 1
  for (int j = 0; j < NIT - 1; j++) run_iter(2 * j, false);
  run_iter(2 * (NIT - 1), true);

  float gscale = 1.f;
  if (MODE == 2) gscale = 1.f / (1.f + __expf(-bias[0]));

  // C/D layout: col = lane&15, row = (lane>>4)*4 + reg
  const int r0 = bm * 256 + wm * 128 + (q << 2);
  const int c0 = bn * 256 + wn * 64 + m16;
  #pragma unroll
  for (int mt = 0; mt < 8; mt++) {
    #pragma unroll
    for (int nt = 0; nt < 4; nt++) {
      const int col = c0 + nt * 16;
      #pragma unroll
      for (int i = 0; i < 4; i++) {
        const int row = r0 + mt * 16 + i;
        float v = acc[mt][nt][i];
        if (MODE == 0) {
          if (col < D_INNER) o0[(size_t)row * D_INNER + col] = f2b(v);
          else               o1[(size_t)row * D_INNER + (col - D_INNER)] = f2b(v);
        } else if (MODE == 1) {
          if (col < D_INNER) v = softplus_f(v + bias[col]);
          if (col < SDT)     o0[(size_t)row * SDT + col] = f2b(v);
        } else {
          of[(size_t)row * D_MODEL + col] = v * gscale;
        }
      }
    }
  }
#undef STAGE_A
#undef STAGE_B
#undef LDA
#undef LDB
#undef MMAQ
#undef BAR
#undef LGK0
}

// ---- scan pass A: per chunk, per (b,d,n): P = prod A_bar, S = chunk inlet ----
__global__ __launch_bounds__(256) void scan_passA(
    const unsigned short* __restrict__ dtBC,
    const unsigned short* __restrict__ xs,
    const float* __restrict__ Alog,
    float* __restrict__ Pb, float* __restrict__ Sb)
{
  const int d = blockIdx.x * 256 + threadIdx.x;
  const int b = blockIdx.y;
  const int c = blockIdx.z;

  float a[NSTATE];
  #pragma unroll
  for (int n = 0; n < NSTATE; n++) a[n] = -__expf(Alog[d * NSTATE + n]);

  float P[NSTATE], S[NSTATE];
  #pragma unroll
  for (int n = 0; n < NSTATE; n++) { P[n] = 1.f; S[n] = 0.f; }

  __shared__ float sB[16][16];
  const size_t bL = (size_t)b * SEQ;
  const int t0c = c * CLEN;
  const int lt = threadIdx.x >> 4, ln = threadIdx.x & 15;

  for (int t0 = t0c; t0 < t0c + CLEN; t0 += 16) {
    __syncthreads();
    sB[lt][ln] = b2f(dtBC[(bL + t0 + lt) * SDT + 2048 + ln]);
    __syncthreads();
    for (int tt = 0; tt < 16; tt++) {
      const size_t rw = bL + t0 + tt;
      const float dt = b2f(dtBC[rw * SDT + d]);
      const float x  = b2f(xs[rw * D_INNER + d]);
      const float dtx = dt * x;
      #pragma unroll
      for (int n = 0; n < NSTATE; n++) {
        const float ab = __expf(dt * a[n]);   // dt>=0, a<0 => clamp(.,20) dead
        P[n] *= ab;
        S[n] = ab * S[n] + dtx * sB[tt][n];
      }
    }
  }
  const size_t base = (((size_t)c * BATCH + b) * D_INNER + d) * NSTATE;
  #pragma unroll
  for (int n = 0; n < NSTATE; n += 4) {
    *(f32x4*)&Pb[base + n] = (f32x4){P[n], P[n+1], P[n+2], P[n+3]};
    *(f32x4*)&Sb[base + n] = (f32x4){S[n], S[n+1], S[n+2], S[n+3]};
  }
}

// ---- scan pass B: sequential combine across chunks; Pb[c] <- h entering c ----
__global__ __launch_bounds__(256) void scan_passB(float* __restrict__ Pb,
                                                  const float* __restrict__ Sb)
{
  const size_t j = (size_t)blockIdx.x * 256 + threadIdx.x;  // (b,d,n) flat
  const size_t stride = (size_t)BATCH * D_INNER * NSTATE;
  float h = 0.f;
  for (int c = 0; c < NCHUNK; c++) {
    const size_t idx = (size_t)c * stride + j;
    const float p = Pb[idx];
    const float s = Sb[idx];
    Pb[idx] = h;
    h = p * h + s;
  }
}

// ---- scan pass C: re-scan chunk with true h0; y=(scan + x*D)*silu(z) ----
// NOTE: yb may alias zb (each thread reads z[rw,d] before writing y[rw,d]).
__global__ __launch_bounds__(256) void scan_passC(
    const unsigned short* __restrict__ dtBC,
    const unsigned short* __restrict__ xs,
    const unsigned short* __restrict__ zb,
    const float* __restrict__ Alog,
    const float* __restrict__ Dv,
    const float* __restrict__ Hb,
    unsigned short* __restrict__ yb)
{
  const int d = blockIdx.x * 256 + threadIdx.x;
  const int b = blockIdx.y;
  const int c = blockIdx.z;

  float a[NSTATE];
  #pragma unroll
  for (int n = 0; n < NSTATE; n++) a[n] = -__expf(Alog[d * NSTATE + n]);

  float h[NSTATE];
  const size_t base = (((size_t)c * BATCH + b) * D_INNER + d) * NSTATE;
  #pragma unroll
  for (int n = 0; n < NSTATE; n += 4) {
    f32x4 v = *(const f32x4*)&Hb[base + n];
    h[n] = v.x; h[n+1] = v.y; h[n+2] = v.z; h[n+3] = v.w;
  }
  const float Dd = Dv[d];

  __shared__ float sB[16][16];
  __shared__ float sC[16][16];
  const size_t bL = (size_t)b * SEQ;
  const int t0c = c * CLEN;
  const int lt = threadIdx.x >> 4, ln = threadIdx.x & 15;

  for (int t0 = t0c; t0 < t0c + CLEN; t0 += 16) {
    __syncthreads();
    {
      const size_t rwb = (bL + t0 + lt) * SDT + 2048;
      sB[lt][ln] = b2f(dtBC[rwb + ln]);
      sC[lt][ln] = b2f(dtBC[rwb + 16 + ln]);
    }
    __syncthreads();
    for (int tt = 0; tt < 16; tt++) {
      const size_t rw = bL + t0 + tt;
      const float dt = b2f(dtBC[rw * SDT + d]);
      const float x  = b2f(xs[rw * D_INNER + d]);
      const float z  = b2f(zb[rw * D_INNER + d]);
      const float dtx = dt * x;
      float y = 0.f;
      #pragma unroll
      for (int n = 0; n < NSTATE; n++) {
        const float ab = __expf(dt * a[n]);
        h[n] = ab * h[n] + dtx * sB[tt][n];
        y += h[n] * sC[tt][n];
      }
      y = (y + x * Dd) * (z / (1.f + __expf(-z)));   // +x*D, *silu(z)
      yb[rw * D_INNER + d] = f2b(y);
    }
  }
}

extern "C" void kernel_launch(void* const* d_in, const int* in_sizes, int n_in,
                              void* d_out, int out_size, void* d_ws, size_t ws_size,
                              hipStream_t stream)
{
  const float* x    = (const float*)d_in[0];   // (4,4096,1024)
  const float* Win  = (const float*)d_in[1];   // (4096,1024)
  const float* Alog = (const float*)d_in[2];   // (2048,16)
  const float* WB   = (const float*)d_in[3];   // (16,2048)
  const float* WC   = (const float*)d_in[4];   // (16,2048)
  const float* Wdt  = (const float*)d_in[5];   // (2048,2048)
  const float* bdt  = (const float*)d_in[6];   // (2048,)
  const float* Dv   = (const float*)d_in[7];   // (2048,)
  const float* gate = (const float*)d_in[8];   // (1,)
  const float* Wout = (const float*)d_in[9];   // (1024,2048)
  float* outp = (float*)d_out;                 // (4,4096,1024) f32

  // ---- d_ws layout: 208 MiB total ----
  char* ws = (char*)d_ws;
  unsigned short* xs    = (unsigned short*)(ws + 0);          // 16384x2048 bf16
  unsigned short* zy    = (unsigned short*)(ws + 67108864);   // z, later y (aliased)
  unsigned short* dtBC  = (unsigned short*)(ws + 134217728);  // 16384x2176 bf16
  unsigned short* Winb  = (unsigned short*)(ws + 205520896);  // 4096x1024 bf16 (8 MB)
  unsigned short* Woutb = (unsigned short*)(ws + 213909504);  // 1024x2048 bf16 (4 MB)

  // ---- d_out (67.1 MB f32) doubles as scratch before final GEMM writes it ----
  char* ob = (char*)d_out;
  float* Pb = (float*)(ob + 0);                               // 16x4x2048x16 f32 (8 MB)
  float* Sb = (float*)(ob + 8388608);                         // (8 MB)
  unsigned short* Wcatb = (unsigned short*)(ob + 16777216);   // 2304x2048 bf16 (9.4 MB)
  unsigned short* xb    = (unsigned short*)(ob + 33554432);   // 16384x1024 bf16 (33.5 MB)

  // prep: input + weight conversions to bf16
  cvt_f2b_kernel<<<16384, 256, 0, stream>>>(x, xb);
  cvt_f2b_kernel<<<4096, 256, 0, stream>>>(Win, Winb);
  cvt_f2b_kernel<<<2048, 256, 0, stream>>>(Wout, Woutb);
  concat_w_kernel<<<(NCATP * D_INNER / 4) / 256, 256, 0, stream>>>(Wdt, WB, WC, Wcatb);

  gemm_bt<0, D_MODEL, N1 / 256><<<dim3(N1 / 256, MTOT / 256), 512, 0, stream>>>(
      xb, Winb, xs, zy, nullptr, nullptr);
  gemm_bt<1, D_INNER, NCATP / 256><<<dim3(NCATP / 256, MTOT / 256), 512, 0, stream>>>(
      xs, Wcatb, dtBC, nullptr, nullptr, bdt);
  scan_passA<<<dim3(D_INNER / 256, BATCH, NCHUNK), 256, 0, stream>>>(
      dtBC, xs, Alog, Pb, Sb);
  scan_passB<<<(BATCH * D_INNER * NSTATE) / 256, 256, 0, stream>>>(Pb, Sb);
  scan_passC<<<dim3(D_INNER / 256, BATCH, NCHUNK), 256, 0, stream>>>(
      dtBC, xs, zy, Alog, Dv, Pb, zy);
  gemm_bt<2, D_INNER, D_MODEL / 256><<<dim3(D_MODEL / 256, MTOT / 256), 512, 0, stream>>>(
      zy, Woutb, nullptr, nullptr, outp, gate);
}

// Round 7
// 1101.391 us; speedup vs baseline: 1.1371x; 1.1371x over previous
//
#include <hip/hip_runtime.h>
#include <hip/hip_bf16.h>
#include <math.h>

#define D_MODEL 1024
#define D_INNER 2048
#define NSTATE  16
#define BATCH   4
#define SEQ     4096
#define MTOT    (BATCH*SEQ)      // 16384
#define SDT     2176             // dtBC row stride: 2048 dt | 16 B | 16 C | 96 pad
#define NCAT    2176             // concat weight rows = 17 * 128 exactly
#define NCHUNK  16
#define CLEN    (SEQ/NCHUNK)     // 256
#define N1      (2*D_INNER)      // 4096

typedef __attribute__((ext_vector_type(8))) __bf16 bf16x8;
typedef __attribute__((ext_vector_type(4))) float f32x4;

__device__ __forceinline__ float b2f(unsigned short u){
  return __uint_as_float(((unsigned int)u) << 16);
}
__device__ __forceinline__ unsigned short f2b(float f){
  unsigned int u = __float_as_uint(f);
  u = (u + 0x7FFFu + ((u >> 16) & 1u)) >> 16;   // RNE
  return (unsigned short)u;
}
__device__ __forceinline__ float softplus_f(float x){
  float r = log1pf(__expf(-fabsf(x)));
  return x > 0.f ? x + r : r;
}

// async 16B global -> LDS (DMA; LDS dst = wave-uniform base + lane*16)
__device__ __forceinline__ void async16(unsigned short* lds, const unsigned short* g){
  __builtin_amdgcn_global_load_lds(
      (const __attribute__((address_space(1))) unsigned int*)g,
      (__attribute__((address_space(3))) unsigned int*)lds, 16, 0, 0);
}

// ---- f32 -> bf16 convert (4 elems/thread) ----
__global__ void cvt_f2b_kernel(const float* __restrict__ src,
                               unsigned short* __restrict__ dst){
  int i = (blockIdx.x * 256 + threadIdx.x) * 4;
  float4 v = *(const float4*)(src + i);
  *(ushort2*)(dst + i)     = (ushort2){f2b(v.x), f2b(v.y)};
  *(ushort2*)(dst + i + 2) = (ushort2){f2b(v.z), f2b(v.w)};
}

// ---- build Wcat(bf16) = [W_dt(2048); W_B(16); W_C(16); zeros(96)] : 2176x2048 ----
__global__ void concat_w_kernel(const float* __restrict__ Wdt,
                                const float* __restrict__ WB,
                                const float* __restrict__ WC,
                                unsigned short* __restrict__ Wcat){
  int idx = blockIdx.x * 256 + threadIdx.x;   // 4-elem granularity
  int row = idx >> 9;                         // 2048 cols = 512 quads/row
  int q   = idx & 511;
  float4 v;
  if      (row < 2048) v = *(const float4*)(Wdt + ((size_t)row * 2048 + q * 4));
  else if (row < 2064) v = *(const float4*)(WB  + ((size_t)(row - 2048) * 2048 + q * 4));
  else if (row < 2080) v = *(const float4*)(WC  + ((size_t)(row - 2064) * 2048 + q * 4));
  else                 v = make_float4(0.f, 0.f, 0.f, 0.f);
  unsigned short* p = Wcat + (size_t)idx * 4;
  *(ushort2*)(p)     = (ushort2){f2b(v.x), f2b(v.y)};
  *(ushort2*)(p + 2) = (ushort2){f2b(v.z), f2b(v.w)};
}

// ============================================================================
// GEMM: C[M,N] = A[M,K] @ W[N,K]^T, bf16 MFMA, fp32 acc, fused epilogues.
//
// 256x128 tile, 512 thr = 8 waves mapped 4m x 2n -> per-wave output 64x64
// (vs r5's 128x32: LDS reads drop 20->16 b128/K-tile/wave, A/B reuse
// balanced). acc[4][4] = 64 AGPR; frag live set a(32)+b(16)=48 arch;
// r5 measured VGPR 88 / zero spill at same budget.
//
// SCHEDULING CHANGE vs r5 (the theory of this rev): NO sched_barrier(0)
// anywhere. r5 fenced every phase region (lgkmcnt+sched_barrier, MMAQ+
// sched_barrier) which blocked the scheduler from overlapping address
// recompute / ds_read issue with MFMA -> VALUBusy 41% serial with MfmaUtil
// 18%. Rule #18 (sched_barrier after lgkmcnt) applies to INLINE-ASM
// ds_reads only; ours are compiler-visible C++ loads (compiler tracks
// deps + emits fine-grained lgkmcnt). This matches the m201 template:
// {ds_read | stage | barrier | lgkmcnt(0) | setprio 16xMFMA setprio | barrier}.
//
// 4-phase iter (2 K-tiles BK=64 per iter), LDS 96 KiB (A 2x32K, B 2x16K),
// counted vmcnt(4) only at P2/P4. Buffer lifetime (CLEANER than r5 —
// stage of a buffer never shares a phase with its reads):
//  P1 rd buf0.A(all)+B(h0)  st buf1.B  <-t0+1 (2 ld)
//  P2 rd buf0.B(h1)         st buf0.A  <-t0+2 (4 ld); vmcnt(4)
//  P3 rd buf1.A(all)+B(h0)  st buf0.B  <-t0+2 (2 ld)
//  P4 rd buf1.B(h1)         st buf1.A  <-t0+3 (4 ld); vmcnt(4)
// Steady-state outstanding at P2: A1(4),B1(2),A0(4) -> vmcnt(4) retires
// A1,B1 (buf1 = next-read tile) keeping A0 in flight; at P4: A0(4),B0(2),
// A1(4) -> vmcnt(4) retires A0,B0 (buf0). Prologue: A0,B0,A1 (10 ld),
// vmcnt(4). Last iter: no stages, vmcnt(0)@P2.
//
// LDS chunk swizzle (bank-conflict-free, verified r5): 16B slot s of row r
// holds k-chunk s^(r&7); stager pre-swizzles the GLOBAL address (linear
// LDS dst). Reads: slot (kk*4+q)^(m16&7); row&7==m16&7 for all frags.
//
// K and GX are template constants (fold stage offsets / grid div).
//
// MODE 0: split cols -> o0=xs (n<2048), o1=z (n>=2048)   [bf16 out]
// MODE 1: n<2048 -> softplus(v + bias[n]); store stride SDT [bf16]
// MODE 2: v * sigmoid(bias[0]); store f32 into of (row stride D_MODEL)
// ============================================================================
template<int MODE, int K, int GX>
__global__ __launch_bounds__(512, 1) void gemm_bt(
    const unsigned short* __restrict__ A,
    const unsigned short* __restrict__ W,
    unsigned short* __restrict__ o0,
    unsigned short* __restrict__ o1,
    float* __restrict__ of,
    const float* __restrict__ bias)
{
  const int tid  = threadIdx.x;
  const int lane = tid & 63;
  const int w    = tid >> 6;            // 0..7
  const int wm   = w >> 1;              // 0..3 : 64-row quarter of tile
  const int wn   = w & 1;               // 0..1 : 64-col half of tile
  const int m16  = lane & 15, q = lane >> 4;

  // XCD-aware bijective swizzle; NWG % 8 == 0 for all launches
  constexpr int NWG = GX * (MTOT / 256);
  int flat = blockIdx.y * GX + blockIdx.x;
  flat = (flat & 7) * (NWG >> 3) + (flat >> 3);
  const int bm = flat / GX;             // const divisor -> magic mul
  const int bn = flat - bm * GX;

  __shared__ unsigned short sA[2][16384];   // 2 x (256 rows x 64 k) = 2 x 32 KB
  __shared__ unsigned short sB[2][8192];    // 2 x (128 rows x 64 k) = 2 x 16 KB

  f32x4 acc[4][4];
  #pragma unroll
  for (int i = 0; i < 4; i++)
    #pragma unroll
    for (int j = 0; j < 4; j++) acc[i][j] = (f32x4){0.f, 0.f, 0.f, 0.f};

  // stager: thread -> (row = tid>>3 within 64-row unit, slot = tid&7);
  // fetched global k-chunk = slot ^ (row&7) (pre-swizzled source)
  const int ch = (tid & 7) ^ ((tid >> 3) & 7);
  const unsigned short* Ag = A + (size_t)(bm * 256 + (tid >> 3)) * K + ch * 8;
  const unsigned short* Wg = W + (size_t)(bn * 128 + (tid >> 3)) * K + ch * 8;

  // one stage unit = 1 async16 = 64 rows x 64 k (8 KB). A half = 2 units.
#define STAGE_A(buf, h, t) do { \
    async16(&sA[buf][(h)*8192 + w*512],        Ag + (size_t)((h)*128    )*K + (t)*64); \
    async16(&sA[buf][(h)*8192 + 4096 + w*512], Ag + (size_t)((h)*128 + 64)*K + (t)*64); \
  } while(0)
#define STAGE_B(buf, t) do { \
    async16(&sB[buf][w*512],        Wg + (size_t)(t)*64); \
    async16(&sB[buf][4096 + w*512], Wg + (size_t)64*K + (t)*64); \
  } while(0)

  // fragment reads: row r, k-chunk kc=(kk*4+q) lives at slot kc^(r&7); r&7==m16&7
#define LDA(dst, buf) do { \
    _Pragma("unroll") for (int mt = 0; mt < 4; mt++) \
    _Pragma("unroll") for (int kk = 0; kk < 2; kk++) { \
      const int row_ = wm*64 + mt*16 + m16; \
      dst[mt][kk] = *(const bf16x8*)&sA[buf][row_*64 + (((kk*4 + q) ^ (m16 & 7)) << 3)]; \
    } } while(0)
#define LDB(dst, buf, nh) do { \
    _Pragma("unroll") for (int nt = 0; nt < 2; nt++) \
    _Pragma("unroll") for (int kk = 0; kk < 2; kk++) { \
      const int row_ = wn*64 + (nh)*32 + nt*16 + m16; \
      dst[nt][kk] = *(const bf16x8*)&sB[buf][row_*64 + (((kk*4 + q) ^ (m16 & 7)) << 3)]; \
    } } while(0)

#define MMAQ(Aa, Bb, NH) do { \
    __builtin_amdgcn_s_setprio(1); \
    _Pragma("unroll") for (int kk = 0; kk < 2; kk++) \
    _Pragma("unroll") for (int mt = 0; mt < 4; mt++) \
    _Pragma("unroll") for (int nt = 0; nt < 2; nt++) \
      acc[mt][(NH)*2 + nt] = __builtin_amdgcn_mfma_f32_16x16x32_bf16( \
          Aa[mt][kk], Bb[nt][kk], acc[mt][(NH)*2 + nt], 0, 0, 0); \
    __builtin_amdgcn_s_setprio(0); \
  } while(0)

#define BAR()  asm volatile("s_barrier" ::: "memory")
#define LGK0() asm volatile("s_waitcnt lgkmcnt(0)" ::: "memory")

  // ---- prologue: buf0 <- tile0 (A 4ld + B 2ld), buf1.A <- tile1 (4ld)
  STAGE_A(0, 0, 0); STAGE_A(0, 1, 0); STAGE_B(0, 0);
  STAGE_A(1, 0, 1); STAGE_A(1, 1, 1);
  asm volatile("s_waitcnt vmcnt(4)" ::: "memory");   // buf0 complete; buf1.A in flight
  BAR();

  auto run_iter = [&](int t0, bool last) {
    bf16x8 a[4][2], b[2][2];
    // ---- P1: buf0, B-half0 (A full) ----
    LDA(a, 0); LDB(b, 0, 0);
    STAGE_B(1, t0 + 1);
    BAR(); LGK0();
    MMAQ(a, b, 0);
    BAR();
    // ---- P2: buf0, B-half1 (a held) ----
    LDB(b, 0, 1);
    if (!last) { STAGE_A(0, 0, t0 + 2); STAGE_A(0, 1, t0 + 2); }
    BAR(); LGK0();
    MMAQ(a, b, 1);
    if (last) asm volatile("s_waitcnt vmcnt(0)" ::: "memory");
    else      asm volatile("s_waitcnt vmcnt(4)" ::: "memory");
    BAR();
    // ---- P3: buf1, B-half0 (A full) ----
    LDA(a, 1); LDB(b, 1, 0);
    if (!last) STAGE_B(0, t0 + 2);
    BAR(); LGK0();
    MMAQ(a, b, 0);
    BAR();
    // ---- P4: buf1, B-half1 (a held) ----
    LDB(b, 1, 1);
    if (!last) { STAGE_A(1, 0, t0 + 3); STAGE_A(1, 1, t0 + 3); }
    BAR(); LGK0();
    MMAQ(a, b, 1);
    if (!last) asm volatile("s_waitcnt vmcnt(4)" ::: "memory");
    BAR();
  };

  constexpr int NIT = K >> 7;          // K / 128 (two 64-K tiles per iter)
  #pragma unroll 1
  for (int j = 0; j < NIT - 1; j++) run_iter(2 * j, false);
  run_iter(2 * (NIT - 1), true);

  float gscale = 1.f;
  if (MODE == 2) gscale = 1.f / (1.f + __expf(-bias[0]));

  // C/D layout: col = lane&15, row = (lane>>4)*4 + reg
  const int r0 = bm * 256 + wm * 64 + (q << 2);
  const int c0 = bn * 128 + wn * 64 + m16;
  #pragma unroll
  for (int mt = 0; mt < 4; mt++) {
    #pragma unroll
    for (int nt = 0; nt < 4; nt++) {
      const int col = c0 + nt * 16;
      #pragma unroll
      for (int i = 0; i < 4; i++) {
        const int row = r0 + mt * 16 + i;
        float v = acc[mt][nt][i];
        if (MODE == 0) {
          if (col < D_INNER) o0[(size_t)row * D_INNER + col] = f2b(v);
          else               o1[(size_t)row * D_INNER + (col - D_INNER)] = f2b(v);
        } else if (MODE == 1) {
          if (col < D_INNER) v = softplus_f(v + bias[col]);
          o0[(size_t)row * SDT + col] = f2b(v);
        } else {
          of[(size_t)row * D_MODEL + col] = v * gscale;
        }
      }
    }
  }
#undef STAGE_A
#undef STAGE_B
#undef LDA
#undef LDB
#undef MMAQ
#undef BAR
#undef LGK0
}

// ---- scan pass A: per chunk, per (b,d,n): P = prod A_bar, S = chunk inlet ----
__global__ __launch_bounds__(256) void scan_passA(
    const unsigned short* __restrict__ dtBC,
    const unsigned short* __restrict__ xs,
    const float* __restrict__ Alog,
    float* __restrict__ Pb, float* __restrict__ Sb)
{
  const int d = blockIdx.x * 256 + threadIdx.x;
  const int b = blockIdx.y;
  const int c = blockIdx.z;

  float a[NSTATE];
  #pragma unroll
  for (int n = 0; n < NSTATE; n++) a[n] = -__expf(Alog[d * NSTATE + n]);

  float P[NSTATE], S[NSTATE];
  #pragma unroll
  for (int n = 0; n < NSTATE; n++) { P[n] = 1.f; S[n] = 0.f; }

  __shared__ float sB[16][16];
  const size_t bL = (size_t)b * SEQ;
  const int t0c = c * CLEN;
  const int lt = threadIdx.x >> 4, ln = threadIdx.x & 15;

  for (int t0 = t0c; t0 < t0c + CLEN; t0 += 16) {
    __syncthreads();
    sB[lt][ln] = b2f(dtBC[(bL + t0 + lt) * SDT + 2048 + ln]);
    __syncthreads();
    for (int tt = 0; tt < 16; tt++) {
      const size_t rw = bL + t0 + tt;
      const float dt = b2f(dtBC[rw * SDT + d]);
      const float x  = b2f(xs[rw * D_INNER + d]);
      const float dtx = dt * x;
      #pragma unroll
      for (int n = 0; n < NSTATE; n++) {
        const float ab = __expf(dt * a[n]);   // dt>=0, a<0 => clamp(.,20) dead
        P[n] *= ab;
        S[n] = ab * S[n] + dtx * sB[tt][n];
      }
    }
  }
  const size_t base = (((size_t)c * BATCH + b) * D_INNER + d) * NSTATE;
  #pragma unroll
  for (int n = 0; n < NSTATE; n += 4) {
    *(f32x4*)&Pb[base + n] = (f32x4){P[n], P[n+1], P[n+2], P[n+3]};
    *(f32x4*)&Sb[base + n] = (f32x4){S[n], S[n+1], S[n+2], S[n+3]};
  }
}

// ---- scan pass B: sequential combine across chunks; Pb[c] <- h entering c ----
__global__ __launch_bounds__(256) void scan_passB(float* __restrict__ Pb,
                                                  const float* __restrict__ Sb)
{
  const size_t j = (size_t)blockIdx.x * 256 + threadIdx.x;  // (b,d,n) flat
  const size_t stride = (size_t)BATCH * D_INNER * NSTATE;
  float h = 0.f;
  for (int c = 0; c < NCHUNK; c++) {
    const size_t idx = (size_t)c * stride + j;
    const float p = Pb[idx];
    const float s = Sb[idx];
    Pb[idx] = h;
    h = p * h + s;
  }
}

// ---- scan pass C: re-scan chunk with true h0; y=(scan + x*D)*silu(z) ----
// NOTE: yb may alias zb (each thread reads z[rw,d] before writing y[rw,d]).
__global__ __launch_bounds__(256) void scan_passC(
    const unsigned short* __restrict__ dtBC,
    const unsigned short* __restrict__ xs,
    const unsigned short* __restrict__ zb,
    const float* __restrict__ Alog,
    const float* __restrict__ Dv,
    const float* __restrict__ Hb,
    unsigned short* __restrict__ yb)
{
  const int d = blockIdx.x * 256 + threadIdx.x;
  const int b = blockIdx.y;
  const int c = blockIdx.z;

  float a[NSTATE];
  #pragma unroll
  for (int n = 0; n < NSTATE; n++) a[n] = -__expf(Alog[d * NSTATE + n]);

  float h[NSTATE];
  const size_t base = (((size_t)c * BATCH + b) * D_INNER + d) * NSTATE;
  #pragma unroll
  for (int n = 0; n < NSTATE; n += 4) {
    f32x4 v = *(const f32x4*)&Hb[base + n];
    h[n] = v.x; h[n+1] = v.y; h[n+2] = v.z; h[n+3] = v.w;
  }
  const float Dd = Dv[d];

  __shared__ float sB[16][16];
  __shared__ float sC[16][16];
  const size_t bL = (size_t)b * SEQ;
  const int t0c = c * CLEN;
  const int lt = threadIdx.x >> 4, ln = threadIdx.x & 15;

  for (int t0 = t0c; t0 < t0c + CLEN; t0 += 16) {
    __syncthreads();
    {
      const size_t rwb = (bL + t0 + lt) * SDT + 2048;
      sB[lt][ln] = b2f(dtBC[rwb + ln]);
      sC[lt][ln] = b2f(dtBC[rwb + 16 + ln]);
    }
    __syncthreads();
    for (int tt = 0; tt < 16; tt++) {
      const size_t rw = bL + t0 + tt;
      const float dt = b2f(dtBC[rw * SDT + d]);
      const float x  = b2f(xs[rw * D_INNER + d]);
      const float z  = b2f(zb[rw * D_INNER + d]);
      const float dtx = dt * x;
      float y = 0.f;
      #pragma unroll
      for (int n = 0; n < NSTATE; n++) {
        const float ab = __expf(dt * a[n]);
        h[n] = ab * h[n] + dtx * sB[tt][n];
        y += h[n] * sC[tt][n];
      }
      y = (y + x * Dd) * (z / (1.f + __expf(-z)));   // +x*D, *silu(z)
      yb[rw * D_INNER + d] = f2b(y);
    }
  }
}

extern "C" void kernel_launch(void* const* d_in, const int* in_sizes, int n_in,
                              void* d_out, int out_size, void* d_ws, size_t ws_size,
                              hipStream_t stream)
{
  const float* x    = (const float*)d_in[0];   // (4,4096,1024)
  const float* Win  = (const float*)d_in[1];   // (4096,1024)
  const float* Alog = (const float*)d_in[2];   // (2048,16)
  const float* WB   = (const float*)d_in[3];   // (16,2048)
  const float* WC   = (const float*)d_in[4];   // (16,2048)
  const float* Wdt  = (const float*)d_in[5];   // (2048,2048)
  const float* bdt  = (const float*)d_in[6];   // (2048,)
  const float* Dv   = (const float*)d_in[7];   // (2048,)
  const float* gate = (const float*)d_in[8];   // (1,)
  const float* Wout = (const float*)d_in[9];   // (1024,2048)
  float* outp = (float*)d_out;                 // (4,4096,1024) f32

  // ---- d_ws layout: 208 MiB total ----
  char* ws = (char*)d_ws;
  unsigned short* xs    = (unsigned short*)(ws + 0);          // 16384x2048 bf16
  unsigned short* zy    = (unsigned short*)(ws + 67108864);   // z, later y (aliased)
  unsigned short* dtBC  = (unsigned short*)(ws + 134217728);  // 16384x2176 bf16
  unsigned short* Winb  = (unsigned short*)(ws + 205520896);  // 4096x1024 bf16 (8 MB)
  unsigned short* Woutb = (unsigned short*)(ws + 213909504);  // 1024x2048 bf16 (4 MB)

  // ---- d_out (67.1 MB f32) doubles as scratch before final GEMM writes it ----
  char* ob = (char*)d_out;
  float* Pb = (float*)(ob + 0);                               // 16x4x2048x16 f32 (8 MB)
  float* Sb = (float*)(ob + 8388608);                         // (8 MB)
  unsigned short* Wcatb = (unsigned short*)(ob + 16777216);   // 2176x2048 bf16 (8.9 MB)
  unsigned short* xb    = (unsigned short*)(ob + 33554432);   // 16384x1024 bf16 (33.5 MB)

  // prep: input + weight conversions to bf16
  cvt_f2b_kernel<<<16384, 256, 0, stream>>>(x, xb);
  cvt_f2b_kernel<<<4096, 256, 0, stream>>>(Win, Winb);
  cvt_f2b_kernel<<<2048, 256, 0, stream>>>(Wout, Woutb);
  concat_w_kernel<<<(NCAT * D_INNER / 4) / 256, 256, 0, stream>>>(Wdt, WB, WC, Wcatb);

  gemm_bt<0, D_MODEL, N1 / 128><<<dim3(N1 / 128, MTOT / 256), 512, 0, stream>>>(
      xb, Winb, xs, zy, nullptr, nullptr);
  gemm_bt<1, D_INNER, NCAT / 128><<<dim3(NCAT / 128, MTOT / 256), 512, 0, stream>>>(
      xs, Wcatb, dtBC, nullptr, nullptr, bdt);
  scan_passA<<<dim3(D_INNER / 256, BATCH, NCHUNK), 256, 0, stream>>>(
      dtBC, xs, Alog, Pb, Sb);
  scan_passB<<<(BATCH * D_INNER * NSTATE) / 256, 256, 0, stream>>>(Pb, Sb);
  scan_passC<<<dim3(D_INNER / 256, BATCH, NCHUNK), 256, 0, stream>>>(
      dtBC, xs, zy, Alog, Dv, Pb, zy);
  gemm_bt<2, D_INNER, D_MODEL / 128><<<dim3(D_MODEL / 128, MTOT / 256), 512, 0, stream>>>(
      zy, Woutb, nullptr, nullptr, outp, gate);
}